// Round 1
// baseline (1024.141 us; speedup 1.0000x reference)
//
#include <hip/hip_runtime.h>
#include <hip/hip_bf16.h>
#include <math.h>

#define N_NODES 100000
#define N_EDGES 1000000
#define ETOT    (N_EDGES + N_NODES)

constexpr float NEG_SLOPE = 0.2f;

// ---------------------------------------------------------------------------
// CSR build: counts -> scan -> scatter (graph shared across all 3 layers)
// ---------------------------------------------------------------------------
__global__ void count_kernel(const int* __restrict__ ei, int* __restrict__ counts) {
    int i = blockIdx.x * blockDim.x + threadIdx.x;
    if (i >= ETOT) return;
    int dst = (i < N_EDGES) ? ei[N_EDGES + i] : (i - N_EDGES);
    atomicAdd(&counts[dst], 1);
}

__global__ __launch_bounds__(1024) void scan_kernel(const int* __restrict__ counts,
                                                    int* __restrict__ offsets, int n) {
    __shared__ int sums[1024];
    int t = threadIdx.x;
    int chunk = (n + 1023) / 1024;
    int begin = t * chunk;
    int end = min(begin + chunk, n);
    int s = 0;
    for (int i = begin; i < end; i++) s += counts[i];
    sums[t] = s;
    __syncthreads();
    // inclusive Hillis-Steele scan
    for (int off = 1; off < 1024; off <<= 1) {
        int v = (t >= off) ? sums[t - off] : 0;
        __syncthreads();
        sums[t] += v;
        __syncthreads();
    }
    int run = (t == 0) ? 0 : sums[t - 1];   // exclusive base
    for (int i = begin; i < end; i++) { offsets[i] = run; run += counts[i]; }
    if (t == 1023) offsets[n] = run;        // == ETOT
}

__global__ void copy_kernel(const int* __restrict__ a, int* __restrict__ b, int n) {
    int i = blockIdx.x * blockDim.x + threadIdx.x;
    if (i < n) b[i] = a[i];
}

__global__ void scatter_kernel(const int* __restrict__ ei, int* __restrict__ cursor,
                               int* __restrict__ csr_src) {
    int i = blockIdx.x * blockDim.x + threadIdx.x;
    if (i >= ETOT) return;
    int src, dst;
    if (i < N_EDGES) { src = ei[i]; dst = ei[N_EDGES + i]; }
    else             { src = dst = i - N_EDGES; }
    int pos = atomicAdd(&cursor[dst], 1);
    csr_src[pos] = src;
}

// ---------------------------------------------------------------------------
// GEMM: Hout[n][j] = sum_k X[n][k] * W[k][j]   (K fixed at 128)
// 16 nodes per block; x staged in LDS; W streamed from L1/L2 (cache-resident)
// ---------------------------------------------------------------------------
template <int OUT>
__global__ __launch_bounds__(256) void gemm_kernel(const float* __restrict__ X,
                                                   const float* __restrict__ W,
                                                   float* __restrict__ Hout) {
    constexpr int NODES  = 16;
    constexpr int GROUPS = 256 / OUT;        // 2 for OUT=128, 4 for OUT=64
    constexpr int NPG    = NODES / GROUPS;   // nodes per group: 8 or 4
    __shared__ float xs[NODES * 128];
    const int t = threadIdx.x;
    const int j = t % OUT;
    const int g = t / OUT;
    const int nodeBase = blockIdx.x * NODES;

    for (int idx = t; idx < NODES * 128; idx += 256)
        xs[idx] = X[nodeBase * 128 + idx];
    __syncthreads();

    float acc[NPG] = {};
    const float* xg = &xs[g * NPG * 128];
    #pragma unroll 4
    for (int k = 0; k < 128; k++) {
        float wv = W[k * OUT + j];
        #pragma unroll
        for (int q = 0; q < NPG; q++)
            acc[q] += xg[q * 128 + k] * wv;
    }
    #pragma unroll
    for (int q = 0; q < NPG; q++)
        Hout[(nodeBase + g * NPG + q) * OUT + j] = acc[q];
}

// ---------------------------------------------------------------------------
// Attention logits: alS[n,h] = sum_c H[n,h,c]*a_src[h,c]; same for alD.
// One CP-lane group per (node, head).
// ---------------------------------------------------------------------------
template <int H, int CP>
__global__ __launch_bounds__(256) void al_kernel(const float* __restrict__ Hf,
                                                 const float* __restrict__ a_s,
                                                 const float* __restrict__ a_d,
                                                 float* __restrict__ alS,
                                                 float* __restrict__ alD, int n) {
    constexpr int CT  = H * CP;
    constexpr int GPB = 256 / CP;
    int gid = blockIdx.x * GPB + threadIdx.x / CP;
    int c   = threadIdx.x % CP;
    if (gid >= n * H) return;
    int node = gid / H, h = gid % H;
    float v  = Hf[node * CT + h * CP + c];
    float vs = v * a_s[h * CP + c];
    float vd = v * a_d[h * CP + c];
    #pragma unroll
    for (int off = CP / 2; off > 0; off >>= 1) {
        vs += __shfl_down(vs, off, CP);
        vd += __shfl_down(vd, off, CP);
    }
    if (c == 0) { alS[gid] = vs; alD[gid] = vd; }
}

// ---------------------------------------------------------------------------
// Aggregation with online softmax: one 64-lane wave per destination node.
// Each lane owns CT/64 channels; (m, d) tracked redundantly per head-group
// (all lanes of a head group compute identical sequences -> no cross-lane).
// ---------------------------------------------------------------------------
template <int CT, int H, bool DO_ELU>
__global__ __launch_bounds__(256) void agg_kernel(const float* __restrict__ Hf,
                                                  const float* __restrict__ alS,
                                                  const float* __restrict__ alD,
                                                  const float* __restrict__ bias,
                                                  const int* __restrict__ offs,
                                                  const int* __restrict__ csr_src,
                                                  float* __restrict__ out, int n) {
    constexpr int CPL = CT / 64;   // channels per lane (2 or 1)
    constexpr int CP  = CT / H;    // channels per head (32 or 64)
    int wave = (blockIdx.x * blockDim.x + threadIdx.x) / 64;
    int lane = threadIdx.x & 63;
    if (wave >= n) return;
    const int node = wave;

    float m[CPL], d[CPL], acc[CPL], ald[CPL];
    int hh[CPL];
    #pragma unroll
    for (int q = 0; q < CPL; q++) {
        int ch = lane + q * 64;
        hh[q]  = ch / CP;
        m[q]   = -INFINITY;
        d[q]   = 0.0f;
        acc[q] = 0.0f;
        ald[q] = alD[node * H + hh[q]];
    }

    const int s0 = offs[node], s1 = offs[node + 1];
    for (int i = s0; i < s1; i++) {
        int s = csr_src[i];
        #pragma unroll
        for (int q = 0; q < CPL; q++) {
            float e = alS[s * H + hh[q]] + ald[q];
            e = (e > 0.0f) ? e : NEG_SLOPE * e;
            float nm = fmaxf(m[q], e);
            float sc = __expf(m[q] - nm);   // first edge: exp(-inf)=0
            float w  = __expf(e - nm);
            float hv = Hf[s * CT + lane + q * 64];
            acc[q] = acc[q] * sc + w * hv;
            d[q]   = d[q] * sc + w;
            m[q]   = nm;
        }
    }

    #pragma unroll
    for (int q = 0; q < CPL; q++) {
        int ch  = lane + q * 64;
        float o = acc[q] / (d[q] + 1e-16f) + bias[ch];
        if (DO_ELU) o = (o > 0.0f) ? o : expm1f(o);
        out[node * CT + ch] = o;
    }
}

// ---------------------------------------------------------------------------
extern "C" void kernel_launch(void* const* d_in, const int* in_sizes, int n_in,
                              void* d_out, int out_size, void* d_ws, size_t ws_size,
                              hipStream_t stream) {
    const float* x   = (const float*)d_in[0];
    const int*   ei  = (const int*)d_in[1];
    const float* W0  = (const float*)d_in[2];
    const float* as0 = (const float*)d_in[3];
    const float* ad0 = (const float*)d_in[4];
    const float* b0  = (const float*)d_in[5];
    const float* W1  = (const float*)d_in[6];
    const float* as1 = (const float*)d_in[7];
    const float* ad1 = (const float*)d_in[8];
    const float* b1  = (const float*)d_in[9];
    const float* W2  = (const float*)d_in[10];
    const float* as2 = (const float*)d_in[11];
    const float* ad2 = (const float*)d_in[12];
    const float* b2  = (const float*)d_in[13];

    char* ws = (char*)d_ws;
    size_t off = 0;
    auto alloc = [&](size_t bytes) -> void* {
        void* p = ws + off;
        off += (bytes + 255) & ~size_t(255);
        return p;
    };
    float* B0     = (float*)alloc((size_t)N_NODES * 128 * sizeof(float)); // h scratch
    float* B1     = (float*)alloc((size_t)N_NODES * 128 * sizeof(float)); // feat ping-pong
    float* alS    = (float*)alloc((size_t)N_NODES * 4 * sizeof(float));
    float* alD    = (float*)alloc((size_t)N_NODES * 4 * sizeof(float));
    int*   counts = (int*)alloc((size_t)N_NODES * sizeof(int));
    int*   offs   = (int*)alloc((size_t)(N_NODES + 1) * sizeof(int));
    int*   cursor = (int*)alloc((size_t)N_NODES * sizeof(int));
    int*   csr    = (int*)alloc((size_t)ETOT * sizeof(int));

    // ---- CSR build (once; shared by all 3 layers) ----
    hipMemsetAsync(counts, 0, (size_t)N_NODES * sizeof(int), stream);
    count_kernel<<<(ETOT + 255) / 256, 256, 0, stream>>>(ei, counts);
    scan_kernel<<<1, 1024, 0, stream>>>(counts, offs, N_NODES);
    copy_kernel<<<(N_NODES + 255) / 256, 256, 0, stream>>>(offs, cursor, N_NODES);
    scatter_kernel<<<(ETOT + 255) / 256, 256, 0, stream>>>(ei, cursor, csr);

    const int GEMM_GRID = N_NODES / 16;          // 6250
    const int AGG_GRID  = (N_NODES + 3) / 4;     // 4 waves/block

    // ---- layer 0: x(128) -> 4 heads x 32, concat, ELU ----
    gemm_kernel<128><<<GEMM_GRID, 256, 0, stream>>>(x, W0, B0);
    al_kernel<4, 32><<<(N_NODES * 4 + 7) / 8, 256, 0, stream>>>(B0, as0, ad0, alS, alD, N_NODES);
    agg_kernel<128, 4, true><<<AGG_GRID, 256, 0, stream>>>(B0, alS, alD, b0, offs, csr, B1, N_NODES);

    // ---- layer 1: 128 -> 4 heads x 32, concat, ELU ----
    gemm_kernel<128><<<GEMM_GRID, 256, 0, stream>>>(B1, W1, B0);
    al_kernel<4, 32><<<(N_NODES * 4 + 7) / 8, 256, 0, stream>>>(B0, as1, ad1, alS, alD, N_NODES);
    agg_kernel<128, 4, true><<<AGG_GRID, 256, 0, stream>>>(B0, alS, alD, b1, offs, csr, B1, N_NODES);

    // ---- layer 2: 128 -> 1 head x 64, mean(=identity), no activation ----
    gemm_kernel<64><<<GEMM_GRID, 256, 0, stream>>>(B1, W2, B0);
    al_kernel<1, 64><<<(N_NODES + 3) / 4, 256, 0, stream>>>(B0, as2, ad2, alS, alD, N_NODES);
    agg_kernel<64, 1, false><<<AGG_GRID, 256, 0, stream>>>(B0, alS, alD, b2, offs, csr,
                                                           (float*)d_out, N_NODES);
}

// Round 2
// 871.806 us; speedup vs baseline: 1.1747x; 1.1747x over previous
//
#include <hip/hip_runtime.h>
#include <hip/hip_bf16.h>
#include <math.h>

#define N_NODES 100000
#define N_EDGES 1000000
#define ETOT    (N_EDGES + N_NODES)

constexpr float NEG_SLOPE = 0.2f;

// ---------------------------------------------------------------------------
// CSR build: counts -> 3-level scan -> scatter (graph shared across 3 layers)
// ---------------------------------------------------------------------------
__global__ void count_kernel(const int* __restrict__ ei, int* __restrict__ counts) {
    int i = blockIdx.x * blockDim.x + threadIdx.x;
    if (i >= ETOT) return;
    int dst = (i < N_EDGES) ? ei[N_EDGES + i] : (i - N_EDGES);
    atomicAdd(&counts[dst], 1);
}

// A: per-block sums of 1024 counts (256 thr x 4 elems, int4 loads)
__global__ __launch_bounds__(256) void block_sum_kernel(const int* __restrict__ counts,
                                                        int* __restrict__ blockSums, int n) {
    int b = blockIdx.x, t = threadIdx.x;
    int base = b * 1024 + t * 4;
    int s = 0;
    if (base + 3 < n) {
        int4 v = *reinterpret_cast<const int4*>(counts + base);
        s = v.x + v.y + v.z + v.w;
    } else {
        for (int i = 0; i < 4; i++) if (base + i < n) s += counts[base + i];
    }
    #pragma unroll
    for (int off = 32; off > 0; off >>= 1) s += __shfl_down(s, off);
    __shared__ int wsum[4];
    int lane = t & 63, wv = t >> 6;
    if (lane == 0) wsum[wv] = s;
    __syncthreads();
    if (t == 0) blockSums[b] = wsum[0] + wsum[1] + wsum[2] + wsum[3];
}

// B: scan the (<=256) block sums -> exclusive block bases
__global__ __launch_bounds__(256) void scan_sums_kernel(const int* __restrict__ blockSums,
                                                        int* __restrict__ blockBase, int nb) {
    __shared__ int sh[256];
    int t = threadIdx.x;
    int v = (t < nb) ? blockSums[t] : 0;
    sh[t] = v;
    __syncthreads();
    for (int off = 1; off < 256; off <<= 1) {
        int u = (t >= off) ? sh[t - off] : 0;
        __syncthreads();
        sh[t] += u;
        __syncthreads();
    }
    if (t < nb) blockBase[t] = sh[t] - v;  // exclusive
}

// C: final exclusive offsets (+ fused cursor init)
__global__ __launch_bounds__(256) void scan_final_kernel(const int* __restrict__ counts,
                                                         const int* __restrict__ blockBase,
                                                         int* __restrict__ offsets,
                                                         int* __restrict__ cursor, int n) {
    int b = blockIdx.x, t = threadIdx.x;
    int base = b * 1024 + t * 4;
    int c[4] = {0, 0, 0, 0};
    if (base + 3 < n) {
        int4 v = *reinterpret_cast<const int4*>(counts + base);
        c[0] = v.x; c[1] = v.y; c[2] = v.z; c[3] = v.w;
    } else {
        for (int i = 0; i < 4; i++) if (base + i < n) c[i] = counts[base + i];
    }
    int tsum = c[0] + c[1] + c[2] + c[3];
    int x = tsum;
    int lane = t & 63, wv = t >> 6;
    #pragma unroll
    for (int off = 1; off < 64; off <<= 1) {
        int u = __shfl_up(x, off);
        if (lane >= off) x += u;
    }
    __shared__ int wsum[4];
    if (lane == 63) wsum[wv] = x;
    __syncthreads();
    int wbase = 0;
    for (int w = 0; w < wv; w++) wbase += wsum[w];
    int run = blockBase[b] + wbase + (x - tsum);   // exclusive base for this thread
    for (int i = 0; i < 4; i++) {
        if (base + i < n) { offsets[base + i] = run; cursor[base + i] = run; run += c[i]; }
    }
    if (b == 0 && t == 0) offsets[n] = ETOT;
}

__global__ void scatter_kernel(const int* __restrict__ ei, int* __restrict__ cursor,
                               int* __restrict__ csr_src) {
    int i = blockIdx.x * blockDim.x + threadIdx.x;
    if (i >= ETOT) return;
    int src, dst;
    if (i < N_EDGES) { src = ei[i]; dst = ei[N_EDGES + i]; }
    else             { src = dst = i - N_EDGES; }
    int pos = atomicAdd(&cursor[dst], 1);
    csr_src[pos] = src;
}

// ---------------------------------------------------------------------------
// GEMM: Hout[n][j] = sum_k X[n][k] * W[k][j]   (K fixed at 128)
// ---------------------------------------------------------------------------
template <int OUT>
__global__ __launch_bounds__(256) void gemm_kernel(const float* __restrict__ X,
                                                   const float* __restrict__ W,
                                                   float* __restrict__ Hout) {
    constexpr int NODES  = 16;
    constexpr int GROUPS = 256 / OUT;
    constexpr int NPG    = NODES / GROUPS;
    __shared__ float xs[NODES * 128];
    const int t = threadIdx.x;
    const int j = t % OUT;
    const int g = t / OUT;
    const int nodeBase = blockIdx.x * NODES;

    for (int idx = t; idx < NODES * 128; idx += 256)
        xs[idx] = X[nodeBase * 128 + idx];
    __syncthreads();

    float acc[NPG] = {};
    const float* xg = &xs[g * NPG * 128];
    #pragma unroll 4
    for (int k = 0; k < 128; k++) {
        float wv = W[k * OUT + j];
        #pragma unroll
        for (int q = 0; q < NPG; q++)
            acc[q] += xg[q * 128 + k] * wv;
    }
    #pragma unroll
    for (int q = 0; q < NPG; q++)
        Hout[(nodeBase + g * NPG + q) * OUT + j] = acc[q];
}

// ---------------------------------------------------------------------------
// Attention logits
// ---------------------------------------------------------------------------
template <int H, int CP>
__global__ __launch_bounds__(256) void al_kernel(const float* __restrict__ Hf,
                                                 const float* __restrict__ a_s,
                                                 const float* __restrict__ a_d,
                                                 float* __restrict__ alS,
                                                 float* __restrict__ alD, int n) {
    constexpr int CT  = H * CP;
    constexpr int GPB = 256 / CP;
    int gid = blockIdx.x * GPB + threadIdx.x / CP;
    int c   = threadIdx.x % CP;
    if (gid >= n * H) return;
    int node = gid / H, h = gid % H;
    float v  = Hf[node * CT + h * CP + c];
    float vs = v * a_s[h * CP + c];
    float vd = v * a_d[h * CP + c];
    #pragma unroll
    for (int off = CP / 2; off > 0; off >>= 1) {
        vs += __shfl_down(vs, off, CP);
        vd += __shfl_down(vd, off, CP);
    }
    if (c == 0) { alS[gid] = vs; alD[gid] = vd; }
}

// ---------------------------------------------------------------------------
// Aggregation with online softmax: one 64-lane wave per destination node.
// ---------------------------------------------------------------------------
template <int CT, int H, bool DO_ELU>
__global__ __launch_bounds__(256) void agg_kernel(const float* __restrict__ Hf,
                                                  const float* __restrict__ alS,
                                                  const float* __restrict__ alD,
                                                  const float* __restrict__ bias,
                                                  const int* __restrict__ offs,
                                                  const int* __restrict__ csr_src,
                                                  float* __restrict__ out, int n) {
    constexpr int CPL = CT / 64;
    constexpr int CP  = CT / H;
    int wave = (blockIdx.x * blockDim.x + threadIdx.x) / 64;
    int lane = threadIdx.x & 63;
    if (wave >= n) return;
    const int node = wave;

    float m[CPL], d[CPL], acc[CPL], ald[CPL];
    int hh[CPL];
    #pragma unroll
    for (int q = 0; q < CPL; q++) {
        int ch = lane + q * 64;
        hh[q]  = ch / CP;
        m[q]   = -INFINITY;
        d[q]   = 0.0f;
        acc[q] = 0.0f;
        ald[q] = alD[node * H + hh[q]];
    }

    const int s0 = offs[node], s1 = offs[node + 1];
    for (int i = s0; i < s1; i++) {
        int s = csr_src[i];
        #pragma unroll
        for (int q = 0; q < CPL; q++) {
            float e = alS[s * H + hh[q]] + ald[q];
            e = (e > 0.0f) ? e : NEG_SLOPE * e;
            float nm = fmaxf(m[q], e);
            float sc = __expf(m[q] - nm);
            float w  = __expf(e - nm);
            float hv = Hf[s * CT + lane + q * 64];
            acc[q] = acc[q] * sc + w * hv;
            d[q]   = d[q] * sc + w;
            m[q]   = nm;
        }
    }

    #pragma unroll
    for (int q = 0; q < CPL; q++) {
        int ch  = lane + q * 64;
        float o = acc[q] / (d[q] + 1e-16f) + bias[ch];
        if (DO_ELU) o = (o > 0.0f) ? o : expm1f(o);
        out[node * CT + ch] = o;
    }
}

// ---------------------------------------------------------------------------
extern "C" void kernel_launch(void* const* d_in, const int* in_sizes, int n_in,
                              void* d_out, int out_size, void* d_ws, size_t ws_size,
                              hipStream_t stream) {
    const float* x   = (const float*)d_in[0];
    const int*   ei  = (const int*)d_in[1];
    const float* W0  = (const float*)d_in[2];
    const float* as0 = (const float*)d_in[3];
    const float* ad0 = (const float*)d_in[4];
    const float* b0  = (const float*)d_in[5];
    const float* W1  = (const float*)d_in[6];
    const float* as1 = (const float*)d_in[7];
    const float* ad1 = (const float*)d_in[8];
    const float* b1  = (const float*)d_in[9];
    const float* W2  = (const float*)d_in[10];
    const float* as2 = (const float*)d_in[11];
    const float* ad2 = (const float*)d_in[12];
    const float* b2  = (const float*)d_in[13];

    char* ws = (char*)d_ws;
    size_t off = 0;
    auto alloc = [&](size_t bytes) -> void* {
        void* p = ws + off;
        off += (bytes + 255) & ~size_t(255);
        return p;
    };
    float* B0      = (float*)alloc((size_t)N_NODES * 128 * sizeof(float));
    float* B1      = (float*)alloc((size_t)N_NODES * 128 * sizeof(float));
    float* alS     = (float*)alloc((size_t)N_NODES * 4 * sizeof(float));
    float* alD     = (float*)alloc((size_t)N_NODES * 4 * sizeof(float));
    int*   counts  = (int*)alloc((size_t)N_NODES * sizeof(int));
    int*   offs    = (int*)alloc((size_t)(N_NODES + 1) * sizeof(int));
    int*   cursor  = (int*)alloc((size_t)N_NODES * sizeof(int));
    int*   csr     = (int*)alloc((size_t)ETOT * sizeof(int));
    int*   bsums   = (int*)alloc(256 * sizeof(int));
    int*   bbase   = (int*)alloc(256 * sizeof(int));

    const int NB = (N_NODES + 1023) / 1024;   // 98

    // ---- CSR build ----
    hipMemsetAsync(counts, 0, (size_t)N_NODES * sizeof(int), stream);
    count_kernel<<<(ETOT + 255) / 256, 256, 0, stream>>>(ei, counts);
    block_sum_kernel<<<NB, 256, 0, stream>>>(counts, bsums, N_NODES);
    scan_sums_kernel<<<1, 256, 0, stream>>>(bsums, bbase, NB);
    scan_final_kernel<<<NB, 256, 0, stream>>>(counts, bbase, offs, cursor, N_NODES);
    scatter_kernel<<<(ETOT + 255) / 256, 256, 0, stream>>>(ei, cursor, csr);

    const int GEMM_GRID = N_NODES / 16;
    const int AGG_GRID  = (N_NODES + 3) / 4;

    // ---- layer 0 ----
    gemm_kernel<128><<<GEMM_GRID, 256, 0, stream>>>(x, W0, B0);
    al_kernel<4, 32><<<(N_NODES * 4 + 7) / 8, 256, 0, stream>>>(B0, as0, ad0, alS, alD, N_NODES);
    agg_kernel<128, 4, true><<<AGG_GRID, 256, 0, stream>>>(B0, alS, alD, b0, offs, csr, B1, N_NODES);

    // ---- layer 1 ----
    gemm_kernel<128><<<GEMM_GRID, 256, 0, stream>>>(B1, W1, B0);
    al_kernel<4, 32><<<(N_NODES * 4 + 7) / 8, 256, 0, stream>>>(B0, as1, ad1, alS, alD, N_NODES);
    agg_kernel<128, 4, true><<<AGG_GRID, 256, 0, stream>>>(B0, alS, alD, b1, offs, csr, B1, N_NODES);

    // ---- layer 2 ----
    gemm_kernel<64><<<GEMM_GRID, 256, 0, stream>>>(B1, W2, B0);
    al_kernel<1, 64><<<(N_NODES + 3) / 4, 256, 0, stream>>>(B0, as2, ad2, alS, alD, N_NODES);
    agg_kernel<64, 1, false><<<AGG_GRID, 256, 0, stream>>>(B0, alS, alD, b2, offs, csr,
                                                           (float*)d_out, N_NODES);
}